// Round 13
// baseline (149.637 us; speedup 1.0000x reference)
//
#include <hip/hip_runtime.h>
#include <stdint.h>

#define M_TOTAL 32768   // B*T
#define NUMS    512
#define DIM     1024
#define TOPK    33

typedef __bf16 bf16_t;
typedef bf16_t bf16x8 __attribute__((ext_vector_type(8)));
typedef float  f32x4  __attribute__((ext_vector_type(4)));
typedef unsigned short ushort_t;

__device__ __forceinline__ ushort_t f2bf(float f) {
    union { float f; uint32_t u; } x; x.f = f;
    uint32_t r = x.u + 0x7FFFu + ((x.u >> 16) & 1u);
    return (ushort_t)(r >> 16);
}
__device__ __forceinline__ float bf2f(uint32_t u) {
    union { uint32_t u; float f; } x; x.u = u << 16;
    return x.f;
}

#define GLDS16(g, l) __builtin_amdgcn_global_load_lds( \
    (const __attribute__((address_space(1))) void*)(g), \
    (__attribute__((address_space(3))) void*)(l), 16, 0, 0)

// ---------------------------------------------------------------------------
// cvtprep: blocks 0..2047: data fp32 -> dataB bf16, XCD-aligned writes.
// blocks 2048..2559: mem fp32 -> memB bf16 + memT bf16 (transposed).
// ---------------------------------------------------------------------------
__global__ __launch_bounds__(256)
void cvtprep_kernel(const float* __restrict__ data, const float* __restrict__ mem,
                    ushort_t* __restrict__ dataB, ushort_t* __restrict__ memB,
                    ushort_t* __restrict__ memT) {
    __shared__ float tile[32][33];
    const int bid = blockIdx.x;
    const int t   = threadIdx.x;
    if (bid < 2048) {
        const int x = bid & 7;        // XCD
        const int j = bid >> 3;       // 0..255
        size_t i = ((size_t)x * 4096 + (size_t)j * 16) * DIM + t * 8;
#pragma unroll
        for (int it = 0; it < 8; ++it, i += 2048) {
            const float4 v0 = *(const float4*)(data + i);
            const float4 v1 = *(const float4*)(data + i + 4);
            union { ushort_t us[8]; uint4 v; } pk;
            pk.us[0] = f2bf(v0.x); pk.us[1] = f2bf(v0.y);
            pk.us[2] = f2bf(v0.z); pk.us[3] = f2bf(v0.w);
            pk.us[4] = f2bf(v1.x); pk.us[5] = f2bf(v1.y);
            pk.us[6] = f2bf(v1.z); pk.us[7] = f2bf(v1.w);
            *(uint4*)(dataB + i) = pk.v;
        }
    } else {
        const int pb = bid - 2048;
        const int bi = pb & 15;
        const int bj = pb >> 4;
        const int r  = t >> 3;
        const int c4 = (t & 7) * 4;
        const float4 v = *(const float4*)(mem + (size_t)(bi * 32 + r) * DIM + bj * 32 + c4);
        ushort4 b;
        b.x = f2bf(v.x); b.y = f2bf(v.y); b.z = f2bf(v.z); b.w = f2bf(v.w);
        *(ushort4*)(memB + (size_t)(bi * 32 + r) * DIM + bj * 32 + c4) = b;
        tile[r][c4 + 0] = v.x; tile[r][c4 + 1] = v.y;
        tile[r][c4 + 2] = v.z; tile[r][c4 + 3] = v.w;
        __syncthreads();
        ushort4 o;
        o.x = f2bf(tile[c4 + 0][r]); o.y = f2bf(tile[c4 + 1][r]);
        o.z = f2bf(tile[c4 + 2][r]); o.w = f2bf(tile[c4 + 3][r]);
        *(ushort4*)(memT + (size_t)(bj * 32 + r) * NUMS + bi * 32 + c4) = o;
    }
}

// ---------------------------------------------------------------------------
// G1: att = sigmoid(dataB @ memB^T / 32). 128x128, BK=64, 2-phase dbuf with
// DRAIN-AFTER-MFMA (catalog minimal T3): STAGE(t+1) -> MFMA(t) -> vmcnt(0) ->
// s_barrier. The t+1 fetch latency hides under MFMA(t) instead of being
// serially exposed at a pre-MFMA __syncthreads (the R8/m97 failure mode).
// LDS 64KB: A0@0 B0@16384 A1@32768 B1@49152 (literal offsets -> LLVM can
// prove disjointness, no spurious drains). 2 blocks/CU.
// ---------------------------------------------------------------------------
__global__ __launch_bounds__(256, 2)
void g1_kernel(const ushort_t* __restrict__ dataB,
               const ushort_t* __restrict__ memB,
               ushort_t* __restrict__ att) {
    __shared__ __align__(16) unsigned char smem[65536];
    const int t    = threadIdx.x;
    const int lane = t & 63;
    const int wid  = t >> 6;      // 0..3
    const int wr   = wid >> 1;    // 0..1
    const int wc   = wid & 1;     // 0..1
    const int wg = (blockIdx.x & 7) * 128 + (blockIdx.x >> 3);
    const int m0 = (wg >> 2) * 128;
    const int n0 = (wg & 3) * 128;

    f32x4 zero = {0.f, 0.f, 0.f, 0.f};
    f32x4 acc[4][4];
#pragma unroll
    for (int m = 0; m < 4; ++m)
#pragma unroll
        for (int n = 0; n < 4; ++n) acc[m][n] = zero;

    const int srcoff = (((lane & 7) ^ (lane >> 3)) & 7) * 8;
    const ushort_t* aS = dataB + (size_t)(m0 + wid * 32 + (lane >> 3)) * DIM + srcoff;
    const ushort_t* bS = memB  + (size_t)(n0 + wid * 32 + (lane >> 3)) * DIM + srcoff;

#define G1_STAGE(TT_, BOFF_) {                                                  \
        unsigned char* da = smem + (BOFF_) + wid * 4096 + lane * 16;            \
        unsigned char* db = smem + (BOFF_) + 16384 + wid * 4096 + lane * 16;    \
        const ushort_t* sa = aS + (TT_) * 64;                                   \
        const ushort_t* sb = bS + (TT_) * 64;                                   \
        GLDS16(sa,            da);        GLDS16(sb,            db);            \
        GLDS16(sa +  8 * DIM, da + 1024); GLDS16(sb +  8 * DIM, db + 1024);     \
        GLDS16(sa + 16 * DIM, da + 2048); GLDS16(sb + 16 * DIM, db + 2048);     \
        GLDS16(sa + 24 * DIM, da + 3072); GLDS16(sb + 24 * DIM, db + 3072); }

#define G1_COMP(BOFF_)                                                          \
    _Pragma("unroll") for (int ki = 0; ki < 2; ++ki) {                          \
        const int ch = ki * 4 + (lane >> 4);                                    \
        bf16x8 af[4], bfr[4];                                                   \
        _Pragma("unroll") for (int m = 0; m < 4; ++m) {                         \
            const int row = wr * 64 + m * 16 + (lane & 15);                     \
            af[m] = *(const bf16x8*)(smem + (BOFF_) + row * 128                 \
                                     + ((ch ^ (row & 7)) << 4));                \
        }                                                                       \
        _Pragma("unroll") for (int n = 0; n < 4; ++n) {                         \
            const int col = wc * 64 + n * 16 + (lane & 15);                     \
            bfr[n] = *(const bf16x8*)(smem + (BOFF_) + 16384 + col * 128        \
                                      + ((ch ^ (col & 7)) << 4));               \
        }                                                                       \
        _Pragma("unroll") for (int m = 0; m < 4; ++m)                           \
            _Pragma("unroll") for (int n = 0; n < 4; ++n)                       \
                acc[m][n] = __builtin_amdgcn_mfma_f32_16x16x32_bf16(            \
                    af[m], bfr[n], acc[m][n], 0, 0, 0);                         \
    }

#define DRAIN_BAR                                                               \
    asm volatile("s_waitcnt vmcnt(0)" ::: "memory");                            \
    __builtin_amdgcn_s_barrier();                                               \
    __builtin_amdgcn_sched_barrier(0);

    G1_STAGE(0, 0)
    DRAIN_BAR
    for (int tb = 0; tb < 8; ++tb) {
        G1_STAGE(2 * tb + 1, 32768)          // prefetch odd tile into buf1
        G1_COMP(0)                            // compute even tile from buf0
        DRAIN_BAR
        if (tb < 7) G1_STAGE(2 * tb + 2, 0)   // prefetch even tile into buf0
        G1_COMP(32768)                        // compute odd tile from buf1
        DRAIN_BAR
    }
#undef G1_STAGE
#undef G1_COMP

    // ---- epilogue: sigmoid -> bf16 att tile [128][128] in LDS, coalesced out
    ushort_t* lAtt = (ushort_t*)smem;
#pragma unroll
    for (int m = 0; m < 4; ++m)
#pragma unroll
        for (int n = 0; n < 4; ++n)
#pragma unroll
            for (int reg = 0; reg < 4; ++reg) {
                const int row = wr * 64 + m * 16 + (lane >> 4) * 4 + reg;
                const int col = wc * 64 + n * 16 + (lane & 15);
                const float x = acc[m][n][reg] * 0.03125f;   // /sqrt(1024)
                const float s = 1.0f / (1.0f + __expf(-x));
                lAtt[row * 128 + col] = f2bf(s);
            }
    __syncthreads();
    {
        const uint4* lsrc = (const uint4*)lAtt;
#pragma unroll
        for (int i = 0; i < 8; ++i) {
            const int idx = i * 256 + t;
            const int r   = idx >> 4;
            const int c16 = idx & 15;
            *(uint4*)(att + (size_t)(m0 + r) * 512 + n0 + c16 * 8) = lsrc[idx];
        }
    }
}

// ---------------------------------------------------------------------------
// topk: temporal[row] = mean of top-33 of att[row][:] via ballot radix-select.
// ---------------------------------------------------------------------------
__global__ __launch_bounds__(256, 8)
void topk_kernel(const ushort_t* __restrict__ att,
                 float* __restrict__ temporal) {
    const int t    = threadIdx.x;
    const int lane = t & 63;
    const int wid  = t >> 6;
    const int base = blockIdx.x * 16 + wid * 4;

    for (int ri = 0; ri < 4; ++ri) {
        const int row = base + ri;
        const uint4 rv = *(const uint4*)(att + (size_t)row * 512 + lane * 8);
        uint32_t u[8];
        u[0] = rv.x & 0xFFFFu; u[1] = rv.x >> 16;
        u[2] = rv.y & 0xFFFFu; u[3] = rv.y >> 16;
        u[4] = rv.z & 0xFFFFu; u[5] = rv.z >> 16;
        u[6] = rv.w & 0xFFFFu; u[7] = rv.w >> 16;
        uint32_t tc = 0;
#pragma unroll
        for (int b = 14; b >= 0; --b) {
            const uint32_t cand = tc | (1u << b);
            int c = 0;
#pragma unroll
            for (int j = 0; j < 8; ++j)
                c += __popcll(__ballot(u[j] >= cand));
            if (c >= TOPK) tc = cand;
        }
        float sgt = 0.f; int cgt = 0;
#pragma unroll
        for (int j = 0; j < 8; ++j) {
            if (u[j] > tc) { sgt += bf2f(u[j]); cgt++; }
        }
#pragma unroll
        for (int off = 32; off >= 1; off >>= 1) {
            sgt += __shfl_xor(sgt, off);
            cgt += __shfl_xor(cgt, off);
        }
        if (lane == 0)
            temporal[row] = (sgt + (float)(TOPK - cgt) * bf2f(tc)) * (1.0f / 33.0f);
    }
}

// ---------------------------------------------------------------------------
// G2: aug = att bf16 @ memT^T. Same drain-after-MFMA 2-phase dbuf.
// 128x128, BK=64, 8 K-steps, XCD-swizzled.
// ---------------------------------------------------------------------------
__global__ __launch_bounds__(256, 2)
void g2_kernel(const ushort_t* __restrict__ att,
               const ushort_t* __restrict__ memT,
               float* __restrict__ aug) {
    __shared__ __align__(16) unsigned char smem[65536];
    const int t    = threadIdx.x;
    const int lane = t & 63;
    const int wid  = t >> 6;
    const int wr   = wid >> 1;
    const int wc   = wid & 1;
    const int wg = (blockIdx.x & 7) * 256 + (blockIdx.x >> 3);
    const int m0 = (wg >> 3) * 128;
    const int n0 = (wg & 7) * 128;

    f32x4 zero = {0.f, 0.f, 0.f, 0.f};
    f32x4 acc[4][4];
#pragma unroll
    for (int m = 0; m < 4; ++m)
#pragma unroll
        for (int n = 0; n < 4; ++n) acc[m][n] = zero;

    const int srcoff = (((lane & 7) ^ (lane >> 3)) & 7) * 8;
    const ushort_t* aS = att  + (size_t)(m0 + wid * 32 + (lane >> 3)) * 512 + srcoff;
    const ushort_t* bS = memT + (size_t)(n0 + wid * 32 + (lane >> 3)) * 512 + srcoff;

#define G2_STAGE(TT_, BOFF_) {                                                  \
        unsigned char* da = smem + (BOFF_) + wid * 4096 + lane * 16;            \
        unsigned char* db = smem + (BOFF_) + 16384 + wid * 4096 + lane * 16;    \
        const ushort_t* sa = aS + (TT_) * 64;                                   \
        const ushort_t* sb = bS + (TT_) * 64;                                   \
        GLDS16(sa,            da);        GLDS16(sb,            db);            \
        GLDS16(sa +  8 * 512, da + 1024); GLDS16(sb +  8 * 512, db + 1024);     \
        GLDS16(sa + 16 * 512, da + 2048); GLDS16(sb + 16 * 512, db + 2048);     \
        GLDS16(sa + 24 * 512, da + 3072); GLDS16(sb + 24 * 512, db + 3072); }

#define G2_COMP(BOFF_)                                                          \
    _Pragma("unroll") for (int ki = 0; ki < 2; ++ki) {                          \
        const int ch = ki * 4 + (lane >> 4);                                    \
        bf16x8 af[4], bfr[4];                                                   \
        _Pragma("unroll") for (int m = 0; m < 4; ++m) {                         \
            const int row = wr * 64 + m * 16 + (lane & 15);                     \
            af[m] = *(const bf16x8*)(smem + (BOFF_) + row * 128                 \
                                     + ((ch ^ (row & 7)) << 4));                \
        }                                                                       \
        _Pragma("unroll") for (int n = 0; n < 4; ++n) {                         \
            const int col = wc * 64 + n * 16 + (lane & 15);                     \
            bfr[n] = *(const bf16x8*)(smem + (BOFF_) + 16384 + col * 128        \
                                      + ((ch ^ (col & 7)) << 4));               \
        }                                                                       \
        _Pragma("unroll") for (int m = 0; m < 4; ++m)                           \
            _Pragma("unroll") for (int n = 0; n < 4; ++n)                       \
                acc[m][n] = __builtin_amdgcn_mfma_f32_16x16x32_bf16(            \
                    af[m], bfr[n], acc[m][n], 0, 0, 0);                         \
    }

    G2_STAGE(0, 0)
    DRAIN_BAR
    for (int tb = 0; tb < 4; ++tb) {
        G2_STAGE(2 * tb + 1, 32768)
        G2_COMP(0)
        DRAIN_BAR
        if (tb < 3) G2_STAGE(2 * tb + 2, 0)
        G2_COMP(32768)
        DRAIN_BAR
    }
#undef G2_STAGE
#undef G2_COMP
#undef DRAIN_BAR

#pragma unroll
    for (int m = 0; m < 4; ++m)
#pragma unroll
        for (int n = 0; n < 4; ++n)
#pragma unroll
            for (int reg = 0; reg < 4; ++reg) {
                const int row = m0 + wr * 64 + m * 16 + (lane >> 4) * 4 + reg;
                const int col = n0 + wc * 64 + n * 16 + (lane & 15);
                aug[(size_t)row * DIM + col] = acc[m][n][reg];
            }
}

// ---------------------------------------------------------------------------
extern "C" void kernel_launch(void* const* d_in, const int* in_sizes, int n_in,
                              void* d_out, int out_size, void* d_ws, size_t ws_size,
                              hipStream_t stream) {
    const float* data = (const float*)d_in[0];   // [16,2048,1024]
    const float* mem  = (const float*)d_in[1];   // [512,1024]
    float* temporal = (float*)d_out;             // [32768]
    float* aug      = (float*)d_out + M_TOTAL;   // [32768,1024] fp32 (128MB)

    ushort_t* memB = (ushort_t*)d_ws;                    // 1MB
    ushort_t* memT = memB + (size_t)NUMS * DIM;          // 1MB
    ushort_t* attw = memT + (size_t)DIM * NUMS;          // 32MB
    ushort_t* dataB = (ushort_t*)aug;                    // 64MB, consumed pre-g2

    cvtprep_kernel<<<2560, 256, 0, stream>>>(data, mem, dataB, memB, memT);
    g1_kernel<<<(M_TOTAL / 128) * (NUMS / 128), 256, 0, stream>>>(dataB, memB, attw);
    topk_kernel<<<M_TOTAL / 16, 256, 0, stream>>>(attw, temporal);
    g2_kernel<<<(M_TOTAL / 128) * (DIM / 128), 256, 0, stream>>>(attw, memT, aug);
}

// Round 14
// 135.389 us; speedup vs baseline: 1.1052x; 1.1052x over previous
//
#include <hip/hip_runtime.h>
#include <stdint.h>

#define M_TOTAL 32768   // B*T
#define NUMS    512
#define DIM     1024
#define TOPK    33

typedef __bf16 bf16_t;
typedef bf16_t bf16x8 __attribute__((ext_vector_type(8)));
typedef float  f32x4  __attribute__((ext_vector_type(4)));
typedef unsigned short ushort_t;
typedef unsigned char  uchar_t;

__device__ __forceinline__ ushort_t f2bf(float f) {
    union { float f; uint32_t u; } x; x.f = f;
    uint32_t r = x.u + 0x7FFFu + ((x.u >> 16) & 1u);
    return (ushort_t)(r >> 16);
}
__device__ __forceinline__ float bf2f(uint32_t u) {
    union { uint32_t u; float f; } x; x.u = u << 16;
    return x.f;
}
__device__ __forceinline__ uint32_t pk4_fp8(float a, float b, float c, float d) {
    uint32_t w = 0;
    w = __builtin_amdgcn_cvt_pk_fp8_f32(a, b, w, false);   // bytes 0,1
    w = __builtin_amdgcn_cvt_pk_fp8_f32(c, d, w, true);    // bytes 2,3
    return w;
}

#define GLDS16(g, l) __builtin_amdgcn_global_load_lds( \
    (const __attribute__((address_space(1))) void*)(g), \
    (__attribute__((address_space(3))) void*)(l), 16, 0, 0)

// ---------------------------------------------------------------------------
// cvtprep: blocks 0..2047: data fp32 -> dataF8 e4m3 (XCD-aligned writes).
// blocks 2048..2559: mem fp32 -> memF8 e4m3 (x16 scale) + memT bf16 (transp).
// ---------------------------------------------------------------------------
__global__ __launch_bounds__(256)
void cvtprep_kernel(const float* __restrict__ data, const float* __restrict__ mem,
                    uchar_t* __restrict__ dataF8, uchar_t* __restrict__ memF8,
                    ushort_t* __restrict__ memT) {
    __shared__ float tile[32][33];
    const int bid = blockIdx.x;
    const int t   = threadIdx.x;
    if (bid < 2048) {
        const int x = bid & 7;        // XCD
        const int j = bid >> 3;       // 0..255
        size_t i = ((size_t)x * 4096 + (size_t)j * 16) * DIM + t * 8;
#pragma unroll
        for (int it = 0; it < 8; ++it, i += 2048) {
            const float4 v0 = *(const float4*)(data + i);
            const float4 v1 = *(const float4*)(data + i + 4);
            uint2 pk;
            pk.x = pk4_fp8(v0.x, v0.y, v0.z, v0.w);
            pk.y = pk4_fp8(v1.x, v1.y, v1.z, v1.w);
            *(uint2*)(dataF8 + i) = pk;
        }
    } else {
        const int pb = bid - 2048;
        const int bi = pb & 15;        // 0..15 (NUMS/32)
        const int bj = pb >> 4;        // 0..31 (DIM/32)
        const int r  = t >> 3;
        const int c4 = (t & 7) * 4;
        const float4 v = *(const float4*)(mem + (size_t)(bi * 32 + r) * DIM + bj * 32 + c4);
        // fp8 copy, x16 scale (exact pow2; puts weights in e4m3 normal range)
        *(uint32_t*)(memF8 + (size_t)(bi * 32 + r) * DIM + bj * 32 + c4) =
            pk4_fp8(v.x * 16.f, v.y * 16.f, v.z * 16.f, v.w * 16.f);
        tile[r][c4 + 0] = v.x; tile[r][c4 + 1] = v.y;
        tile[r][c4 + 2] = v.z; tile[r][c4 + 3] = v.w;
        __syncthreads();
        ushort4 o;
        o.x = f2bf(tile[c4 + 0][r]); o.y = f2bf(tile[c4 + 1][r]);
        o.z = f2bf(tile[c4 + 2][r]); o.w = f2bf(tile[c4 + 3][r]);
        *(ushort4*)(memT + (size_t)(bj * 32 + r) * NUMS + bi * 32 + c4) = o;
    }
}

// ---------------------------------------------------------------------------
// G1 (fp8): att = sigmoid(dataF8 @ memF8^T / 512), bf16 store.
// 128x128 tile, K-step = 128 fp8 (8 steps), single-buffer 32KB LDS, 256 thr =
// 4 waves (2x2), wave tile 64x64. Same BYTE layout as the bf16 kernel:
// 128-B rows, 8x16-B slots, slot s of row r holds global 16-B chunk s^(r&7).
// Per step: 4 ki x 16 MFMA (fp8_fp8 16x16x32) = 64 MFMA/wave — 2x compute
// per barrier vs bf16, half the staged bytes overall.
// Fragment: 8 B (long). ki selects 16-B chunk 2ki+(q>>1), half (q&1)*8, q=lane>>4.
// ---------------------------------------------------------------------------
__global__ __launch_bounds__(256, 4)
void g1_kernel(const uchar_t* __restrict__ dataF8,
               const uchar_t* __restrict__ memF8,
               ushort_t* __restrict__ att) {
    __shared__ __align__(16) unsigned char smem[32768];
    const int t    = threadIdx.x;
    const int lane = t & 63;
    const int wid  = t >> 6;      // 0..3
    const int wr   = wid >> 1;    // 0..1
    const int wc   = wid & 1;     // 0..1
    const int wg = (blockIdx.x & 7) * 128 + (blockIdx.x >> 3);
    const int m0 = (wg >> 2) * 128;
    const int n0 = (wg & 3) * 128;

    f32x4 zero = {0.f, 0.f, 0.f, 0.f};
    f32x4 acc[4][4];
#pragma unroll
    for (int m = 0; m < 4; ++m)
#pragma unroll
        for (int n = 0; n < 4; ++n) acc[m][n] = zero;

    // staging: wave wid covers 32 rows (4 GLDS x 8 rows); 128-B k-slice per row
    const int srcoff = (((lane & 7) ^ (lane >> 3)) & 7) * 16;   // bytes
    const uchar_t* aS = dataF8 + (size_t)(m0 + wid * 32 + (lane >> 3)) * DIM + srcoff;
    const uchar_t* bS = memF8  + (size_t)(n0 + wid * 32 + (lane >> 3)) * DIM + srcoff;

    const int q  = lane >> 4;       // 0..3
    const int o8 = (q & 1) * 8;     // half-slot byte offset

    for (int tt = 0; tt < 8; ++tt) {
        {
            unsigned char* da = smem + wid * 4096 + lane * 16;
            unsigned char* db = da + 16384;
            const uchar_t* sa = aS + tt * 128;
            const uchar_t* sb = bS + tt * 128;
            GLDS16(sa,            da);        GLDS16(sb,            db);
            GLDS16(sa +  8 * DIM, da + 1024); GLDS16(sb +  8 * DIM, db + 1024);
            GLDS16(sa + 16 * DIM, da + 2048); GLDS16(sb + 16 * DIM, db + 2048);
            GLDS16(sa + 24 * DIM, da + 3072); GLDS16(sb + 24 * DIM, db + 3072);
        }
        __syncthreads();
#pragma unroll
        for (int ki = 0; ki < 4; ++ki) {
            const int c16 = ki * 2 + (q >> 1);    // 16-B chunk of this k-slice
            long af[4], bfr[4];
#pragma unroll
            for (int m = 0; m < 4; ++m) {
                const int row = wr * 64 + m * 16 + (lane & 15);
                af[m] = *(const long*)(smem + row * 128
                        + ((c16 ^ (row & 7)) << 4) + o8);
            }
#pragma unroll
            for (int n = 0; n < 4; ++n) {
                const int col = wc * 64 + n * 16 + (lane & 15);
                bfr[n] = *(const long*)(smem + 16384 + col * 128
                        + ((c16 ^ (col & 7)) << 4) + o8);
            }
#pragma unroll
            for (int m = 0; m < 4; ++m)
#pragma unroll
                for (int n = 0; n < 4; ++n)
                    acc[m][n] = __builtin_amdgcn_mfma_f32_16x16x32_fp8_fp8(
                        af[m], bfr[n], acc[m][n], 0, 0, 0);
        }
        __syncthreads();
    }

    // ---- epilogue: sigmoid(acc/512) -> bf16 att tile [128][128], coalesced out
    ushort_t* lAtt = (ushort_t*)smem;
#pragma unroll
    for (int m = 0; m < 4; ++m)
#pragma unroll
        for (int n = 0; n < 4; ++n)
#pragma unroll
            for (int reg = 0; reg < 4; ++reg) {
                const int row = wr * 64 + m * 16 + (lane >> 4) * 4 + reg;
                const int col = wc * 64 + n * 16 + (lane & 15);
                const float x = acc[m][n][reg] * 0.001953125f;  // /(32*16)
                const float s = 1.0f / (1.0f + __expf(-x));
                lAtt[row * 128 + col] = f2bf(s);
            }
    __syncthreads();
    {
        const uint4* lsrc = (const uint4*)lAtt;
#pragma unroll
        for (int i = 0; i < 8; ++i) {
            const int idx = i * 256 + t;
            const int r   = idx >> 4;
            const int c16 = idx & 15;
            *(uint4*)(att + (size_t)(m0 + r) * 512 + n0 + c16 * 8) = lsrc[idx];
        }
    }
}

// ---------------------------------------------------------------------------
// topk: temporal[row] = mean of top-33 of att[row][:] via ballot radix-select.
// ---------------------------------------------------------------------------
__global__ __launch_bounds__(256, 8)
void topk_kernel(const ushort_t* __restrict__ att,
                 float* __restrict__ temporal) {
    const int t    = threadIdx.x;
    const int lane = t & 63;
    const int wid  = t >> 6;
    const int base = blockIdx.x * 16 + wid * 4;

    for (int ri = 0; ri < 4; ++ri) {
        const int row = base + ri;
        const uint4 rv = *(const uint4*)(att + (size_t)row * 512 + lane * 8);
        uint32_t u[8];
        u[0] = rv.x & 0xFFFFu; u[1] = rv.x >> 16;
        u[2] = rv.y & 0xFFFFu; u[3] = rv.y >> 16;
        u[4] = rv.z & 0xFFFFu; u[5] = rv.z >> 16;
        u[6] = rv.w & 0xFFFFu; u[7] = rv.w >> 16;
        uint32_t tc = 0;
#pragma unroll
        for (int b = 14; b >= 0; --b) {
            const uint32_t cand = tc | (1u << b);
            int c = 0;
#pragma unroll
            for (int j = 0; j < 8; ++j)
                c += __popcll(__ballot(u[j] >= cand));
            if (c >= TOPK) tc = cand;
        }
        float sgt = 0.f; int cgt = 0;
#pragma unroll
        for (int j = 0; j < 8; ++j) {
            if (u[j] > tc) { sgt += bf2f(u[j]); cgt++; }
        }
#pragma unroll
        for (int off = 32; off >= 1; off >>= 1) {
            sgt += __shfl_xor(sgt, off);
            cgt += __shfl_xor(cgt, off);
        }
        if (lane == 0)
            temporal[row] = (sgt + (float)(TOPK - cgt) * bf2f(tc)) * (1.0f / 33.0f);
    }
}

// ---------------------------------------------------------------------------
// G2: aug = att bf16 @ memT^T. m97-class single-buffer 32KB, 128x128, BK=64,
// 4 waves, XCD-swizzled (R11 version — best measured).
// ---------------------------------------------------------------------------
__global__ __launch_bounds__(256, 4)
void g2_kernel(const ushort_t* __restrict__ att,
               const ushort_t* __restrict__ memT,
               float* __restrict__ aug) {
    __shared__ __align__(16) unsigned char smem[32768];
    const int t    = threadIdx.x;
    const int lane = t & 63;
    const int wid  = t >> 6;
    const int wr   = wid >> 1;
    const int wc   = wid & 1;
    const int wg = (blockIdx.x & 7) * 256 + (blockIdx.x >> 3);
    const int m0 = (wg >> 3) * 128;
    const int n0 = (wg & 7) * 128;

    f32x4 zero = {0.f, 0.f, 0.f, 0.f};
    f32x4 acc[4][4];
#pragma unroll
    for (int m = 0; m < 4; ++m)
#pragma unroll
        for (int n = 0; n < 4; ++n) acc[m][n] = zero;

    const int srcoff = (((lane & 7) ^ (lane >> 3)) & 7) * 8;
    const ushort_t* aS = att  + (size_t)(m0 + wid * 32 + (lane >> 3)) * 512 + srcoff;
    const ushort_t* bS = memT + (size_t)(n0 + wid * 32 + (lane >> 3)) * 512 + srcoff;

    for (int tt = 0; tt < 8; ++tt) {
        {
            unsigned char* da = smem + wid * 4096 + lane * 16;
            unsigned char* db = da + 16384;
            const ushort_t* sa = aS + tt * 64;
            const ushort_t* sb = bS + tt * 64;
            GLDS16(sa,            da);        GLDS16(sb,            db);
            GLDS16(sa +  8 * 512, da + 1024); GLDS16(sb +  8 * 512, db + 1024);
            GLDS16(sa + 16 * 512, da + 2048); GLDS16(sb + 16 * 512, db + 2048);
            GLDS16(sa + 24 * 512, da + 3072); GLDS16(sb + 24 * 512, db + 3072);
        }
        __syncthreads();
#pragma unroll
        for (int ki = 0; ki < 2; ++ki) {
            const int ch = ki * 4 + (lane >> 4);
            bf16x8 af[4], bfr[4];
#pragma unroll
            for (int m = 0; m < 4; ++m) {
                const int row = wr * 64 + m * 16 + (lane & 15);
                af[m] = *(const bf16x8*)(smem + row * 128 + ((ch ^ (row & 7)) << 4));
            }
#pragma unroll
            for (int n = 0; n < 4; ++n) {
                const int col = wc * 64 + n * 16 + (lane & 15);
                bfr[n] = *(const bf16x8*)(smem + 16384 + col * 128 + ((ch ^ (col & 7)) << 4));
            }
#pragma unroll
            for (int m = 0; m < 4; ++m)
#pragma unroll
                for (int n = 0; n < 4; ++n)
                    acc[m][n] = __builtin_amdgcn_mfma_f32_16x16x32_bf16(
                        af[m], bfr[n], acc[m][n], 0, 0, 0);
        }
        __syncthreads();
    }

#pragma unroll
    for (int m = 0; m < 4; ++m)
#pragma unroll
        for (int n = 0; n < 4; ++n)
#pragma unroll
            for (int reg = 0; reg < 4; ++reg) {
                const int row = m0 + wr * 64 + m * 16 + (lane >> 4) * 4 + reg;
                const int col = n0 + wc * 64 + n * 16 + (lane & 15);
                aug[(size_t)row * DIM + col] = acc[m][n][reg];
            }
}

// ---------------------------------------------------------------------------
extern "C" void kernel_launch(void* const* d_in, const int* in_sizes, int n_in,
                              void* d_out, int out_size, void* d_ws, size_t ws_size,
                              hipStream_t stream) {
    const float* data = (const float*)d_in[0];   // [16,2048,1024]
    const float* mem  = (const float*)d_in[1];   // [512,1024]
    float* temporal = (float*)d_out;             // [32768]
    float* aug      = (float*)d_out + M_TOTAL;   // [32768,1024] fp32 (128MB)

    uchar_t*  memF8 = (uchar_t*)d_ws;                       // 512KB (e4m3, x16)
    ushort_t* memT  = (ushort_t*)(memF8 + (size_t)NUMS * DIM);  // 1MB bf16
    ushort_t* attw  = memT + (size_t)DIM * NUMS;            // 32MB bf16
    // dataF8 e4m3 (32MB) lives in the aug output region; consumed pre-g2.
    uchar_t* dataF8 = (uchar_t*)aug;

    cvtprep_kernel<<<2560, 256, 0, stream>>>(data, mem, dataF8, memF8, memT);
    g1_kernel<<<(M_TOTAL / 128) * (NUMS / 128), 256, 0, stream>>>(dataF8, memF8, attw);
    topk_kernel<<<M_TOTAL / 16, 256, 0, stream>>>(attw, temporal);
    g2_kernel<<<(M_TOTAL / 128) * (DIM / 128), 256, 0, stream>>>(attw, memT, aug);
}